// Round 10
// baseline (464.921 us; speedup 1.0000x reference)
//
#include <hip/hip_runtime.h>
#include <stdint.h>

// CrossWinAttention: b=4 n=4 x=y=8 w1=w2=8 d=128, H=4 Dh=32, L=64, NW=256, BH=16.
#define LN_EPS 1e-5f
#define SCALE 0.17677669529663687f   // 32^-0.5
#define KEEPQ 192

typedef __attribute__((ext_vector_type(8))) short short8v;   // 8 bf16
typedef __attribute__((ext_vector_type(4))) float float4v;
typedef __attribute__((ext_vector_type(4))) unsigned int uint4v;

__device__ __forceinline__ short f2bf(float x) {             // RNE f32->bf16
  uint32_t u = __float_as_uint(x);
  uint32_t r = (u + 0x7FFFu + ((u >> 16) & 1u)) >> 16;
  return (short)r;
}
__device__ __forceinline__ float bf2f(short s) {
  return __uint_as_float(((uint32_t)(uint16_t)s) << 16);
}
__device__ __forceinline__ uint32_t pk2(short a, short b) {
  return (uint32_t)(uint16_t)a | ((uint32_t)(uint16_t)b << 16);
}
__device__ __forceinline__ void split3(float x, short &h, short &m, short &l) {
  h = f2bf(x); float r1 = x - bf2f(h);
  m = f2bf(r1); float r2 = r1 - bf2f(m);
  l = f2bf(r2);
}
__device__ __forceinline__ uint32_t fmap(float x) {          // order-preserving map
  uint32_t bb = __float_as_uint(x);
  if ((bb & 0x7FFFFFFFu) == 0u) bb = 0u;                     // -0 -> +0
  return (bb & 0x80000000u) ? ~bb : (bb | 0x80000000u);
}
__device__ __forceinline__ float unmap(uint32_t m) {         // inverse of fmap
  uint32_t b = (m & 0x80000000u) ? (m & 0x7FFFFFFFu) : ~m;
  return __uint_as_float(b);
}

// Exact top-k over 256 values, 4 per lane (element index = lane + 64*s).
// Tie-break: smaller index wins. All 64 lanes must participate.
__device__ __forceinline__ void topk_sel(const float v[4], int k, int lane, bool sel[4]) {
  uint32_t u[4];
  #pragma unroll
  for (int s = 0; s < 4; ++s) u[s] = fmap(v[s]);
  uint32_t prefix = 0u;
  bool exact = false;
  for (int bit = 31; bit >= 0; --bit) {
    uint32_t cand = prefix | (1u << bit);
    int c = 0;
    #pragma unroll
    for (int s = 0; s < 4; ++s) c += __popcll(__ballot(u[s] >= cand));
    if (c >= k) {
      prefix = cand;
      if (c == k) { exact = true; break; }
    }
  }
  if (exact) {
    #pragma unroll
    for (int s = 0; s < 4; ++s) sel[s] = (u[s] >= prefix);
    return;
  }
  const uint32_t T = prefix;
  int gt = 0;
  unsigned long long eb[4];
  #pragma unroll
  for (int s = 0; s < 4; ++s) {
    gt += __popcll(__ballot(u[s] > T));
    eb[s] = __ballot(u[s] == T);
  }
  const int need = k - gt;
  const unsigned long long lm = (1ull << lane) - 1ull;
  int base = 0;
  #pragma unroll
  for (int s = 0; s < 4; ++s) {
    int before = base + __popcll(eb[s] & lm);
    sel[s] = (u[s] > T) || ((u[s] == T) && (before < need));
    base += __popcll(eb[s]);
  }
}

// ---------------- Kernel 1: LN + QKV projection (FROZEN numerics) ----------------
__global__ __launch_bounds__(256) void k_lnproj(
    const float* __restrict__ xq, const float* __restrict__ xk, const float* __restrict__ xv,
    const float* __restrict__ gq, const float* __restrict__ beq,
    const float* __restrict__ gk, const float* __restrict__ bek,
    const float* __restrict__ gv, const float* __restrict__ bev,
    const float* __restrict__ wq, const float* __restrict__ biq,
    const float* __restrict__ wk, const float* __restrict__ bik,
    const float* __restrict__ wv, const float* __restrict__ biv,
    float* __restrict__ qh, short* __restrict__ k0, short* __restrict__ k1,
    short* __restrict__ k2, short* __restrict__ vt)
{
  __shared__ float xs[64 * 132];
  const int tile = blockIdx.x;
  const int t = blockIdx.y;
  const float* x  = (t == 0) ? xq : (t == 1) ? xk : xv;
  const float* g  = (t == 0) ? gq : (t == 1) ? gk : gv;
  const float* be = (t == 0) ? beq : (t == 1) ? bek : bev;
  const float* W  = (t == 0) ? wq : (t == 1) ? wk : wv;
  const float* bi = (t == 0) ? biq : (t == 1) ? bik : biv;
  const int tid = threadIdx.x;

  const float4* xg = (const float4*)(x + (size_t)tile * 64 * 128);
  #pragma unroll
  for (int i = 0; i < 8; ++i) {
    int idx = tid + i * 256;
    int r = idx >> 5;
    int c = (idx & 31) * 4;
    *(float4*)&xs[r * 132 + c] = xg[idx];
  }
  __syncthreads();

  {
    int r = tid >> 2, p = tid & 3;
    float s = 0.f, sq = 0.f;
    #pragma unroll
    for (int c = 0; c < 32; ++c) {
      float vv = xs[r * 132 + p * 32 + c];
      s += vv; sq += vv * vv;
    }
    s += __shfl_xor(s, 1, 64); sq += __shfl_xor(sq, 1, 64);
    s += __shfl_xor(s, 2, 64); sq += __shfl_xor(sq, 2, 64);
    float mean = s * (1.0f / 128.0f);
    float var = sq * (1.0f / 128.0f) - mean * mean;
    float rstd = rsqrtf(var + LN_EPS);
    #pragma unroll
    for (int c = 0; c < 32; ++c) {
      int cc = p * 32 + c;
      xs[r * 132 + cc] = (xs[r * 132 + cc] - mean) * rstd * g[cc] + be[cc];
    }
  }
  __syncthreads();

  const int ty = tid >> 4, tx = tid & 15;
  float acc[4][8];
  #pragma unroll
  for (int i = 0; i < 4; ++i)
    #pragma unroll
    for (int j = 0; j < 8; ++j) acc[i][j] = 0.f;

  #pragma unroll 2
  for (int kk = 0; kk < 128; kk += 4) {
    float aa[4][4];
    #pragma unroll
    for (int i = 0; i < 4; ++i)
      *(float4*)&aa[i][0] = *(const float4*)&xs[(ty * 4 + i) * 132 + kk];
    #pragma unroll
    for (int t2 = 0; t2 < 4; ++t2) {
      const float4 w0 = *(const float4*)&W[(kk + t2) * 128 + tx * 8];
      const float4 w1 = *(const float4*)&W[(kk + t2) * 128 + tx * 8 + 4];
      #pragma unroll
      for (int i = 0; i < 4; ++i) {
        acc[i][0] = fmaf(aa[i][t2], w0.x, acc[i][0]);
        acc[i][1] = fmaf(aa[i][t2], w0.y, acc[i][1]);
        acc[i][2] = fmaf(aa[i][t2], w0.z, acc[i][2]);
        acc[i][3] = fmaf(aa[i][t2], w0.w, acc[i][3]);
        acc[i][4] = fmaf(aa[i][t2], w1.x, acc[i][4]);
        acc[i][5] = fmaf(aa[i][t2], w1.y, acc[i][5]);
        acc[i][6] = fmaf(aa[i][t2], w1.z, acc[i][6]);
        acc[i][7] = fmaf(aa[i][t2], w1.w, acc[i][7]);
      }
    }
  }

  float bias[8];
  #pragma unroll
  for (int j = 0; j < 8; ++j) bias[j] = bi[tx * 8 + j];
  const int b  = tile >> 8;
  const int n  = (tile >> 6) & 3;
  const int l  = ((tile >> 3) & 7) * 8 + (tile & 7);
  const int h  = tx >> 2;
  const int dh0 = (tx & 3) * 8;
  const size_t win = (size_t)(b * 4 + h) * 64 + l;

  if (t == 0) {
    #pragma unroll
    for (int i = 0; i < 4; ++i) {
      int j = n * 64 + ty * 4 + i;
      size_t off = (win * 256 + j) * 32 + dh0;
      float4 o0 = make_float4(acc[i][0] + bias[0], acc[i][1] + bias[1],
                              acc[i][2] + bias[2], acc[i][3] + bias[3]);
      float4 o1 = make_float4(acc[i][4] + bias[4], acc[i][5] + bias[5],
                              acc[i][6] + bias[6], acc[i][7] + bias[7]);
      *(float4*)&qh[off] = o0;
      *(float4*)&qh[off + 4] = o1;
    }
  } else if (t == 1) {
    #pragma unroll
    for (int i = 0; i < 4; ++i) {
      int j = n * 64 + ty * 4 + i;
      size_t off = (win * 256 + j) * 32 + dh0;
      short hh[8], mm[8], ll[8];
      #pragma unroll
      for (int jj = 0; jj < 8; ++jj) {
        float o = acc[i][jj] + bias[jj];
        split3(o, hh[jj], mm[jj], ll[jj]);
      }
      *(uint4*)&k0[off] = make_uint4(pk2(hh[0], hh[1]), pk2(hh[2], hh[3]),
                                     pk2(hh[4], hh[5]), pk2(hh[6], hh[7]));
      *(uint4*)&k1[off] = make_uint4(pk2(mm[0], mm[1]), pk2(mm[2], mm[3]),
                                     pk2(mm[4], mm[5]), pk2(mm[6], mm[7]));
      *(uint4*)&k2[off] = make_uint4(pk2(ll[0], ll[1]), pk2(ll[2], ll[3]),
                                     pk2(ll[4], ll[5]), pk2(ll[6], ll[7]));
    }
  } else {
    short vb[4][8];
    #pragma unroll
    for (int i = 0; i < 4; ++i)
      #pragma unroll
      for (int jj = 0; jj < 8; ++jj)
        vb[i][jj] = f2bf(acc[i][jj] + bias[jj]);
    const int jbase = n * 64 + ty * 4;
    #pragma unroll
    for (int jj = 0; jj < 8; ++jj) {
      size_t off = (win * 32 + dh0 + jj) * 256 + jbase;
      *(uint2*)&vt[off] = make_uint2(pk2(vb[0][jj], vb[1][jj]),
                                     pk2(vb[2][jj], vb[3][jj]));
    }
  }
}

// ---------------- Kernel 2: windowed attention (swapped QK^T, 256-thr blocks) ----
// One block per window, 256 thr = 4 waves; wave wv owns w-tile wt=wv and loops
// all 4 n-units sequentially. 256-thread workgroups (4 waves) remove the
// 8-wave 2-waves/SIMD hardware floor that capped the unified file at 256
// regs/wave (R6-R9: allocator split 128 arch/128 agpr -> u[16] spilled
// ~200 MB). With 4 waves the compiler may use up to 512 regs -> no spill.
__global__ __launch_bounds__(256, 1) void k_attn(
    const float* __restrict__ qh, const short* __restrict__ k0,
    const short* __restrict__ k1, const short* __restrict__ k2,
    const short* __restrict__ vt, float* __restrict__ abar)
{
  __shared__ __align__(16) short ks0s[256][36];   // 18432 B
  __shared__ __align__(16) short ks1s[256][36];   // 18432 B
  __shared__ __align__(16) short vts[32][264];    // 16896 B
  __shared__ __align__(16) short pt[4][16][72];   // 9216 B (per-wave P slab)
  __shared__ float sal[256];                       // 1024 B
  __shared__ float keepf[256];                     // 1024 B   total 65024 B

  const int win = blockIdx.x;
  const int bh = win >> 6, l = win & 63;
  const int b = bh >> 2, h = bh & 3;
  const int tid = threadIdx.x;
  const int lane = tid & 63, wv = tid >> 6;
  const int g = lane >> 4, p = lane & 15;
  const int wt = wv;                          // 4 waves, 4 w-tiles

  const float* qw = qh + (size_t)win * 8192;
  const short* kw2 = k2 + (size_t)win * 8192;

  // ---- stage K hi/mid + V^T into LDS ----
  {
    const uint4* s0 = (const uint4*)(k0 + (size_t)win * 8192);
    const uint4* s1 = (const uint4*)(k1 + (size_t)win * 8192);
    const uint4* sv = (const uint4*)(vt + (size_t)win * 8192);
    #pragma unroll
    for (int i = 0; i < 4; ++i) {
      int ci = tid + i * 256;                  // 1024 uint4 per tensor
      int r = ci >> 2, c8 = (ci & 3) * 8;
      *(uint4*)&ks0s[r][c8] = s0[ci];
      *(uint4*)&ks1s[r][c8] = s1[ci];
      int rv = ci >> 5, c16 = (ci & 31) * 8;
      *(uint4*)&vts[rv][c16] = sv[ci];
    }
  }
  // ---- query saliency (FROZEN summation order) ----
  {
    const float4* qg2 = (const float4*)(qw + (size_t)tid * 32);
    float ss = 0.f;
    #pragma unroll
    for (int i = 0; i < 8; ++i) {
      float4 vv = qg2[i];
      ss += vv.x * vv.x + vv.y * vv.y + vv.z * vv.z + vv.w * vv.w;
    }
    sal[tid] = ss;
  }
  __syncthreads();
  if (wv == 0) {                              // exact top-192 saliency (FROZEN)
    float v[4]; bool selq[4];
    #pragma unroll
    for (int s = 0; s < 4; ++s) v[s] = sal[lane + 64 * s];
    topk_sel(v, KEEPQ, lane, selq);
    #pragma unroll
    for (int s = 0; s < 4; ++s) keepf[lane + 64 * s] = selq[s] ? SCALE : 0.0f;
  }
  __syncthreads();

  float4v pacc0 = {0.f, 0.f, 0.f, 0.f};
  float4v pacc1 = {0.f, 0.f, 0.f, 0.f};
  short* ptw = &pt[wv][0][0];                 // [16][72]

  for (int n = 0; n < 4; ++n) {
    const int qbase = n * 64 + wt * 16;
    const float kfp = keepf[qbase + p];       // per-query (col p) keep factor
    const bool kept = (kfp != 0.0f);

    // ---- Q B-fragment: scale+mask then bf16x3 split (FROZEN values) ----
    short8v aq0, aq1, aq2;
    {
      const float* qrow = qw + (size_t)(qbase + p) * 32 + g * 8;
      float4 qa = *(const float4*)qrow;
      float4 qb = *(const float4*)(qrow + 4);
      float qv[8] = {qa.x, qa.y, qa.z, qa.w, qb.x, qb.y, qb.z, qb.w};
      #pragma unroll
      for (int e = 0; e < 8; ++e) {
        short hh, mm, ll;
        split3(qv[e] * kfp, hh, mm, ll);
        aq0[e] = hh; aq1[e] = mm; aq2[e] = ll;
      }
    }

    // ---- QK^T swapped: S[key 16c+4g+r][query qbase+p]; FROZEN chain ----
    uint4v u[16];
    uint32_t umax = 0u, umin = 0xFFFFFFFFu;
    #pragma unroll
    for (int c = 0; c < 16; ++c) {
      const short8v b0 = *(const short8v*)&ks0s[c * 16 + p][g * 8];
      const short8v b1 = *(const short8v*)&ks1s[c * 16 + p][g * 8];
      const short8v b2 = *(const short8v*)(kw2 + (size_t)(c * 16 + p) * 32 + g * 8);
      float4v a = {0.f, 0.f, 0.f, 0.f};
      a = __builtin_amdgcn_mfma_f32_16x16x32_bf16(b0, aq0, a, 0, 0, 0);
      a = __builtin_amdgcn_mfma_f32_16x16x32_bf16(b0, aq1, a, 0, 0, 0);
      a = __builtin_amdgcn_mfma_f32_16x16x32_bf16(b0, aq2, a, 0, 0, 0);
      a = __builtin_amdgcn_mfma_f32_16x16x32_bf16(b1, aq0, a, 0, 0, 0);
      a = __builtin_amdgcn_mfma_f32_16x16x32_bf16(b1, aq1, a, 0, 0, 0);
      a = __builtin_amdgcn_mfma_f32_16x16x32_bf16(b2, aq0, a, 0, 0, 0);
      #pragma unroll
      for (int r = 0; r < 4; ++r) {
        uint32_t m = fmap(a[r]);
        u[c][r] = m;
        umax = max(umax, m); umin = min(umin, m);
      }
    }
    umax = max(umax, (uint32_t)__shfl_xor((int)umax, 16));
    umin = min(umin, (uint32_t)__shfl_xor((int)umin, 16));
    umax = max(umax, (uint32_t)__shfl_xor((int)umax, 32));
    umin = min(umin, (uint32_t)__shfl_xor((int)umin, 32));
    const float fm = unmap(umax);             // exact row max

    // ---- exact top-64 threshold via bisection (counts are exact ints) ----
    uint32_t piv = 0u; int cnt = 256; int sb = -1; bool bdone = true;
    if (kept) {
      uint32_t diff = umax ^ umin;
      if (diff != 0u) {
        sb = 31 - __clz(diff);
        piv = (sb >= 31) ? 0u : (umax & (0xFFFFFFFFu << (sb + 1)));
        bdone = false;
      } else { piv = umax; }                  // all equal -> tie path
    }
    for (int bit = 31; bit >= 0; --bit) {
      if (__all(bdone)) break;
      uint32_t cand = piv | (1u << bit);
      int cc = 0;
      #pragma unroll
      for (int c = 0; c < 16; ++c) {
        #pragma unroll
        for (int r = 0; r < 4; ++r) cc += (u[c][r] >= cand) ? 1 : 0;
      }
      cc += __shfl_xor(cc, 16);
      cc += __shfl_xor(cc, 32);
      if (!bdone && bit <= sb && cc >= 64) {
        piv = cand; cnt = cc;
        if (cc == 64) bdone = true;
      }
    }
    const uint32_t T = piv;

    // ---- selection mask (bit 4c+r), exact tie-break by key index ----
    uint64_t selm = 0ull;
    if (kept) {
      if (cnt == 64) {
        #pragma unroll
        for (int c = 0; c < 16; ++c)
          #pragma unroll
          for (int r = 0; r < 4; ++r)
            selm |= (u[c][r] >= T) ? (1ull << (4 * c + r)) : 0ull;
      } else {
        // rare: ties at T. Branch is uniform over each query's 4 lanes.
        int gtc = 0;
        #pragma unroll
        for (int c = 0; c < 16; ++c)
          #pragma unroll
          for (int r = 0; r < 4; ++r) gtc += (u[c][r] > T) ? 1 : 0;
        gtc += __shfl_xor(gtc, 16);
        gtc += __shfl_xor(gtc, 32);
        const int need = 64 - gtc;
        uint64_t em = 0ull;
        #pragma unroll
        for (int c = 0; c < 16; ++c)
          #pragma unroll
          for (int r = 0; r < 4; ++r)
            em |= (u[c][r] == T) ? (1ull << (4 * c + r)) : 0ull;
        uint64_t emA = __shfl_xor((unsigned long long)em, 16);
        uint64_t emB = __shfl_xor((unsigned long long)em, 32);
        uint64_t emC = __shfl_xor((unsigned long long)emA, 32);
        uint64_t M0 = (g == 0) ? em : ((g == 1) ? emA : ((g == 2) ? emB : emC));
        uint64_t M1 = (g == 1) ? em : ((g == 0) ? emA : ((g == 3) ? emB : emC));
        uint64_t M2 = (g == 2) ? em : ((g == 3) ? emA : ((g == 0) ? emB : emC));
        uint64_t M3 = (g == 3) ? em : ((g == 2) ? emA : ((g == 1) ? emB : emC));
        int pref = 0;
        #pragma unroll
        for (int c = 0; c < 16; ++c) {
          int n0 = (int)((M0 >> (4 * c)) & 15ull);
          int n1 = (int)((M1 >> (4 * c)) & 15ull);
          int n2 = (int)((M2 >> (4 * c)) & 15ull);
          int n3 = (int)((M3 >> (4 * c)) & 15ull);
          int gs = ((g > 0) ? __popc(n0) : 0) + ((g > 1) ? __popc(n1) : 0)
                 + ((g > 2) ? __popc(n2) : 0);
          int on = (int)((em >> (4 * c)) & 15ull);
          #pragma unroll
          for (int r = 0; r < 4; ++r) {
            bool s2;
            if (u[c][r] > T) s2 = true;
            else if (u[c][r] == T) {
              int before = pref + gs + __popc(on & ((1 << r) - 1));
              s2 = (before < need);
            } else s2 = false;
            selm |= s2 ? (1ull << (4 * c + r)) : 0ull;
          }
          pref += __popc(n0) + __popc(n1) + __popc(n2) + __popc(n3);
        }
      }
    }

    // ---- e = exp(S - fm) on selected; OVERWRITE u in place; esum (FROZEN order) ----
    float esum = 0.f;
    #pragma unroll
    for (int c = 0; c < 16; ++c) {
      #pragma unroll
      for (int r = 0; r < 4; ++r) {
        float e;
        if (kept)
          e = ((selm >> (4 * c + r)) & 1ull) ? __expf(unmap(u[c][r]) - fm) : 0.0f;
        else
          e = (c < 4) ? 0.015625f : 0.0f;    // pruned: uniform 1/64 over first 64 keys
        u[c][r] = __float_as_uint(e);
        esum += e;
      }
    }
    esum += __shfl_xor(esum, 16);
    esum += __shfl_xor(esum, 32);
    const float inv = kept ? (1.0f / esum) : 1.0f;

    // ---- PV: stage P^T per 2-kk block, then MFMA (FROZEN chain order;
    //      n-units chained sequentially into pacc) ----
    #pragma unroll
    for (int t = 0; t < 4; ++t) {
      #pragma unroll
      for (int kq = 0; kq < 2; ++kq) {
        const int kk = 2 * t + kq;
        const int ce = 2 * kk, co = ce + 1;
        uint2 w0 = make_uint2(
            pk2(f2bf(__uint_as_float(u[ce][0]) * inv), f2bf(__uint_as_float(u[ce][1]) * inv)),
            pk2(f2bf(__uint_as_float(u[ce][2]) * inv), f2bf(__uint_as_float(u[ce][3]) * inv)));
        uint2 w1 = make_uint2(
            pk2(f2bf(__uint_as_float(u[co][0]) * inv), f2bf(__uint_as_float(u[co][1]) * inv)),
            pk2(f2bf(__uint_as_float(u[co][2]) * inv), f2bf(__uint_as_float(u[co][3]) * inv)));
        *(uint2*)&ptw[p * 72 + kq * 32 + 4 * g] = w0;
        *(uint2*)&ptw[p * 72 + kq * 32 + 16 + 4 * g] = w1;
      }
      // cross-lane visibility of this wave's writes (no HIP-level dependency)
      asm volatile("s_waitcnt lgkmcnt(0)" ::: "memory");
      __builtin_amdgcn_sched_barrier(0);
      #pragma unroll
      for (int kq = 0; kq < 2; ++kq) {
        const int kk = 2 * t + kq;
        short8v pa = *(const short8v*)&ptw[p * 72 + kq * 32 + 8 * g];
        short8v v0 = *(const short8v*)&vts[p][kk * 32 + 8 * g];
        short8v v1 = *(const short8v*)&vts[16 + p][kk * 32 + 8 * g];
        pacc0 = __builtin_amdgcn_mfma_f32_16x16x32_bf16(pa, v0, pacc0, 0, 0, 0);
        pacc1 = __builtin_amdgcn_mfma_f32_16x16x32_bf16(pa, v1, pacc1, 0, 0, 0);
      }
    }
  }

  // ---- write abar = mean over n (each wave owns its w-tile; no reduction) ----
  #pragma unroll
  for (int rr = 0; rr < 4; ++rr) {
    const int w = wt * 16 + g * 4 + rr;
    size_t o = ((size_t)(b * 64 + l) * 64 + w) * 128 + h * 32;
    abar[o + p] = pacc0[rr] * 0.25f;
    abar[o + 16 + p] = pacc1[rr] * 0.25f;
  }
}

// ---------------- Kernel 3: final projection (FROZEN) ----------------
__global__ __launch_bounds__(256) void k_proj(
    const float* __restrict__ abar, const float* __restrict__ W,
    const float* __restrict__ bi, float* __restrict__ out)
{
  __shared__ float xs[64 * 132];
  const int tile = blockIdx.x;
  const int tid = threadIdx.x;
  const float4* xg = (const float4*)(abar + (size_t)tile * 64 * 128);
  #pragma unroll
  for (int i = 0; i < 8; ++i) {
    int idx = tid + i * 256;
    int r = idx >> 5, c = (idx & 31) * 4;
    *(float4*)&xs[r * 132 + c] = xg[idx];
  }
  __syncthreads();

  const int ty = tid >> 4, tx = tid & 15;
  float acc[4][8];
  #pragma unroll
  for (int i = 0; i < 4; ++i)
    #pragma unroll
    for (int j = 0; j < 8; ++j) acc[i][j] = 0.f;

  #pragma unroll 2
  for (int kk = 0; kk < 128; kk += 4) {
    float aa[4][4];
    #pragma unroll
    for (int i = 0; i < 4; ++i)
      *(float4*)&aa[i][0] = *(const float4*)&xs[(ty * 4 + i) * 132 + kk];
    #pragma unroll
    for (int t2 = 0; t2 < 4; ++t2) {
      const float4 w0 = *(const float4*)&W[(kk + t2) * 128 + tx * 8];
      const float4 w1 = *(const float4*)&W[(kk + t2) * 128 + tx * 8 + 4];
      #pragma unroll
      for (int i = 0; i < 4; ++i) {
        acc[i][0] = fmaf(aa[i][t2], w0.x, acc[i][0]);
        acc[i][1] = fmaf(aa[i][t2], w0.y, acc[i][1]);
        acc[i][2] = fmaf(aa[i][t2], w0.z, acc[i][2]);
        acc[i][3] = fmaf(aa[i][t2], w0.w, acc[i][3]);
        acc[i][4] = fmaf(aa[i][t2], w1.x, acc[i][4]);
        acc[i][5] = fmaf(aa[i][t2], w1.y, acc[i][5]);
        acc[i][6] = fmaf(aa[i][t2], w1.z, acc[i][6]);
        acc[i][7] = fmaf(aa[i][t2], w1.w, acc[i][7]);
      }
    }
  }
  #pragma unroll
  for (int i = 0; i < 4; ++i) {
    size_t row = (size_t)tile * 64 + ty * 4 + i;
    float4 o0 = make_float4(acc[i][0] + bi[tx * 8 + 0], acc[i][1] + bi[tx * 8 + 1],
                            acc[i][2] + bi[tx * 8 + 2], acc[i][3] + bi[tx * 8 + 3]);
    float4 o1 = make_float4(acc[i][4] + bi[tx * 8 + 4], acc[i][5] + bi[tx * 8 + 5],
                            acc[i][6] + bi[tx * 8 + 6], acc[i][7] + bi[tx * 8 + 7]);
    *(float4*)&out[row * 128 + tx * 8] = o0;
    *(float4*)&out[row * 128 + tx * 8 + 4] = o1;
  }
}

extern "C" void kernel_launch(void* const* d_in, const int* in_sizes, int n_in,
                              void* d_out, int out_size, void* d_ws, size_t ws_size,
                              hipStream_t stream) {
  (void)in_sizes; (void)n_in; (void)out_size; (void)ws_size;
  const float* xq   = (const float*)d_in[0];
  const float* xk   = (const float*)d_in[1];
  const float* xv   = (const float*)d_in[2];
  const float* gq   = (const float*)d_in[3];
  const float* beq  = (const float*)d_in[4];
  const float* gk   = (const float*)d_in[5];
  const float* bek  = (const float*)d_in[6];
  const float* gv   = (const float*)d_in[7];
  const float* bev  = (const float*)d_in[8];
  const float* wq   = (const float*)d_in[9];
  const float* biq  = (const float*)d_in[10];
  const float* wk   = (const float*)d_in[11];
  const float* bik  = (const float*)d_in[12];
  const float* wv   = (const float*)d_in[13];
  const float* biv  = (const float*)d_in[14];
  const float* wpr  = (const float*)d_in[15];
  const float* bpr  = (const float*)d_in[16];

  // ws layout (109,051,904 B total == proven footprint):
  char* ws = (char*)d_ws;
  float* qh  = (float*)(ws);                       // 33,554,432 B
  short* k0  = (short*)(ws + 33554432);            // 16,777,216 B
  short* k1  = (short*)(ws + 50331648);            // 16,777,216 B
  short* k2  = (short*)(ws + 67108864);            // 16,777,216 B
  short* vt  = (short*)(ws + 83886080);            // 16,777,216 B
  float* abar = (float*)(ws + 100663296);          //  8,388,608 B

  k_lnproj<<<dim3(1024, 3), 256, 0, stream>>>(xq, xk, xv, gq, beq, gk, bek, gv, bev,
                                              wq, biq, wk, bik, wv, biv,
                                              qh, k0, k1, k2, vt);
  k_attn<<<1024, 256, 0, stream>>>(qh, k0, k1, k2, vt, abar);
  k_proj<<<256, 256, 0, stream>>>(abar, wpr, bpr, (float*)d_out);
}

// Round 11
// 370.600 us; speedup vs baseline: 1.2545x; 1.2545x over previous
//
#include <hip/hip_runtime.h>
#include <stdint.h>

// CrossWinAttention: b=4 n=4 x=y=8 w1=w2=8 d=128, H=4 Dh=32, L=64, NW=256, BH=16.
#define LN_EPS 1e-5f
#define SCALE 0.17677669529663687f   // 32^-0.5
#define KEEPQ 192

typedef __attribute__((ext_vector_type(8))) short short8v;   // 8 bf16
typedef __attribute__((ext_vector_type(4))) float float4v;

__device__ __forceinline__ short f2bf(float x) {             // RNE f32->bf16
  uint32_t u = __float_as_uint(x);
  uint32_t r = (u + 0x7FFFu + ((u >> 16) & 1u)) >> 16;
  return (short)r;
}
__device__ __forceinline__ float bf2f(short s) {
  return __uint_as_float(((uint32_t)(uint16_t)s) << 16);
}
__device__ __forceinline__ uint32_t pk2(short a, short b) {
  return (uint32_t)(uint16_t)a | ((uint32_t)(uint16_t)b << 16);
}
__device__ __forceinline__ void split3(float x, short &h, short &m, short &l) {
  h = f2bf(x); float r1 = x - bf2f(h);
  m = f2bf(r1); float r2 = r1 - bf2f(m);
  l = f2bf(r2);
}
__device__ __forceinline__ uint32_t fmap(float x) {          // order-preserving map
  uint32_t bb = __float_as_uint(x);
  if ((bb & 0x7FFFFFFFu) == 0u) bb = 0u;                     // -0 -> +0
  return (bb & 0x80000000u) ? ~bb : (bb | 0x80000000u);
}
__device__ __forceinline__ float unmap(uint32_t m) {         // inverse of fmap
  uint32_t b = (m & 0x80000000u) ? (m & 0x7FFFFFFFu) : ~m;
  return __uint_as_float(b);
}

// Exact top-k over 256 values, 4 per lane (element index = lane + 64*s).
// Tie-break: smaller index wins. All 64 lanes must participate.
__device__ __forceinline__ void topk_sel(const float v[4], int k, int lane, bool sel[4]) {
  uint32_t u[4];
  #pragma unroll
  for (int s = 0; s < 4; ++s) u[s] = fmap(v[s]);
  uint32_t prefix = 0u;
  bool exact = false;
  for (int bit = 31; bit >= 0; --bit) {
    uint32_t cand = prefix | (1u << bit);
    int c = 0;
    #pragma unroll
    for (int s = 0; s < 4; ++s) c += __popcll(__ballot(u[s] >= cand));
    if (c >= k) {
      prefix = cand;
      if (c == k) { exact = true; break; }
    }
  }
  if (exact) {
    #pragma unroll
    for (int s = 0; s < 4; ++s) sel[s] = (u[s] >= prefix);
    return;
  }
  const uint32_t T = prefix;
  int gt = 0;
  unsigned long long eb[4];
  #pragma unroll
  for (int s = 0; s < 4; ++s) {
    gt += __popcll(__ballot(u[s] > T));
    eb[s] = __ballot(u[s] == T);
  }
  const int need = k - gt;
  const unsigned long long lm = (1ull << lane) - 1ull;
  int base = 0;
  #pragma unroll
  for (int s = 0; s < 4; ++s) {
    int before = base + __popcll(eb[s] & lm);
    sel[s] = (u[s] > T) || ((u[s] == T) && (before < need));
    base += __popcll(eb[s]);
  }
}

// ---------------- Kernel 1: LN + QKV projection (FROZEN numerics) ----------------
__global__ __launch_bounds__(256) void k_lnproj(
    const float* __restrict__ xq, const float* __restrict__ xk, const float* __restrict__ xv,
    const float* __restrict__ gq, const float* __restrict__ beq,
    const float* __restrict__ gk, const float* __restrict__ bek,
    const float* __restrict__ gv, const float* __restrict__ bev,
    const float* __restrict__ wq, const float* __restrict__ biq,
    const float* __restrict__ wk, const float* __restrict__ bik,
    const float* __restrict__ wv, const float* __restrict__ biv,
    float* __restrict__ qh, short* __restrict__ k0, short* __restrict__ k1,
    short* __restrict__ k2, short* __restrict__ vt)
{
  __shared__ float xs[64 * 132];
  const int tile = blockIdx.x;
  const int t = blockIdx.y;
  const float* x  = (t == 0) ? xq : (t == 1) ? xk : xv;
  const float* g  = (t == 0) ? gq : (t == 1) ? gk : gv;
  const float* be = (t == 0) ? beq : (t == 1) ? bek : bev;
  const float* W  = (t == 0) ? wq : (t == 1) ? wk : wv;
  const float* bi = (t == 0) ? biq : (t == 1) ? bik : biv;
  const int tid = threadIdx.x;

  const float4* xg = (const float4*)(x + (size_t)tile * 64 * 128);
  #pragma unroll
  for (int i = 0; i < 8; ++i) {
    int idx = tid + i * 256;
    int r = idx >> 5;
    int c = (idx & 31) * 4;
    *(float4*)&xs[r * 132 + c] = xg[idx];
  }
  __syncthreads();

  {
    int r = tid >> 2, p = tid & 3;
    float s = 0.f, sq = 0.f;
    #pragma unroll
    for (int c = 0; c < 32; ++c) {
      float vv = xs[r * 132 + p * 32 + c];
      s += vv; sq += vv * vv;
    }
    s += __shfl_xor(s, 1, 64); sq += __shfl_xor(sq, 1, 64);
    s += __shfl_xor(s, 2, 64); sq += __shfl_xor(sq, 2, 64);
    float mean = s * (1.0f / 128.0f);
    float var = sq * (1.0f / 128.0f) - mean * mean;
    float rstd = rsqrtf(var + LN_EPS);
    #pragma unroll
    for (int c = 0; c < 32; ++c) {
      int cc = p * 32 + c;
      xs[r * 132 + cc] = (xs[r * 132 + cc] - mean) * rstd * g[cc] + be[cc];
    }
  }
  __syncthreads();

  const int ty = tid >> 4, tx = tid & 15;
  float acc[4][8];
  #pragma unroll
  for (int i = 0; i < 4; ++i)
    #pragma unroll
    for (int j = 0; j < 8; ++j) acc[i][j] = 0.f;

  #pragma unroll 2
  for (int kk = 0; kk < 128; kk += 4) {
    float aa[4][4];
    #pragma unroll
    for (int i = 0; i < 4; ++i)
      *(float4*)&aa[i][0] = *(const float4*)&xs[(ty * 4 + i) * 132 + kk];
    #pragma unroll
    for (int t2 = 0; t2 < 4; ++t2) {
      const float4 w0 = *(const float4*)&W[(kk + t2) * 128 + tx * 8];
      const float4 w1 = *(const float4*)&W[(kk + t2) * 128 + tx * 8 + 4];
      #pragma unroll
      for (int i = 0; i < 4; ++i) {
        acc[i][0] = fmaf(aa[i][t2], w0.x, acc[i][0]);
        acc[i][1] = fmaf(aa[i][t2], w0.y, acc[i][1]);
        acc[i][2] = fmaf(aa[i][t2], w0.z, acc[i][2]);
        acc[i][3] = fmaf(aa[i][t2], w0.w, acc[i][3]);
        acc[i][4] = fmaf(aa[i][t2], w1.x, acc[i][4]);
        acc[i][5] = fmaf(aa[i][t2], w1.y, acc[i][5]);
        acc[i][6] = fmaf(aa[i][t2], w1.z, acc[i][6]);
        acc[i][7] = fmaf(aa[i][t2], w1.w, acc[i][7]);
      }
    }
  }

  float bias[8];
  #pragma unroll
  for (int j = 0; j < 8; ++j) bias[j] = bi[tx * 8 + j];
  const int b  = tile >> 8;
  const int n  = (tile >> 6) & 3;
  const int l  = ((tile >> 3) & 7) * 8 + (tile & 7);
  const int h  = tx >> 2;
  const int dh0 = (tx & 3) * 8;
  const size_t win = (size_t)(b * 4 + h) * 64 + l;

  if (t == 0) {
    #pragma unroll
    for (int i = 0; i < 4; ++i) {
      int j = n * 64 + ty * 4 + i;
      size_t off = (win * 256 + j) * 32 + dh0;
      float4 o0 = make_float4(acc[i][0] + bias[0], acc[i][1] + bias[1],
                              acc[i][2] + bias[2], acc[i][3] + bias[3]);
      float4 o1 = make_float4(acc[i][4] + bias[4], acc[i][5] + bias[5],
                              acc[i][6] + bias[6], acc[i][7] + bias[7]);
      *(float4*)&qh[off] = o0;
      *(float4*)&qh[off + 4] = o1;
    }
  } else if (t == 1) {
    #pragma unroll
    for (int i = 0; i < 4; ++i) {
      int j = n * 64 + ty * 4 + i;
      size_t off = (win * 256 + j) * 32 + dh0;
      short hh[8], mm[8], ll[8];
      #pragma unroll
      for (int jj = 0; jj < 8; ++jj) {
        float o = acc[i][jj] + bias[jj];
        split3(o, hh[jj], mm[jj], ll[jj]);
      }
      *(uint4*)&k0[off] = make_uint4(pk2(hh[0], hh[1]), pk2(hh[2], hh[3]),
                                     pk2(hh[4], hh[5]), pk2(hh[6], hh[7]));
      *(uint4*)&k1[off] = make_uint4(pk2(mm[0], mm[1]), pk2(mm[2], mm[3]),
                                     pk2(mm[4], mm[5]), pk2(mm[6], mm[7]));
      *(uint4*)&k2[off] = make_uint4(pk2(ll[0], ll[1]), pk2(ll[2], ll[3]),
                                     pk2(ll[4], ll[5]), pk2(ll[6], ll[7]));
    }
  } else {
    short vb[4][8];
    #pragma unroll
    for (int i = 0; i < 4; ++i)
      #pragma unroll
      for (int jj = 0; jj < 8; ++jj)
        vb[i][jj] = f2bf(acc[i][jj] + bias[jj]);
    const int jbase = n * 64 + ty * 4;
    #pragma unroll
    for (int jj = 0; jj < 8; ++jj) {
      size_t off = (win * 32 + dh0 + jj) * 256 + jbase;
      *(uint2*)&vt[off] = make_uint2(pk2(vb[0][jj], vb[1][jj]),
                                     pk2(vb[2][jj], vb[3][jj]));
    }
  }
}

// ---------------- Kernel 2: windowed attention (swapped QK^T, float bisect) -----
// One block per window, 256 thr = 4 waves; wave wv owns w-tile wt=wv, loops 4 n.
// R10 lesson: holding BOTH acc[16] (MFMA out) and u[16] (fmap'd) = 128 regs ->
// total >256 -> 1 wave/SIMD. Fix: bisect in FLOAT domain directly on acc
// (fmap is an order isomorphism: fmap(v)>=cand <=> v>=unmap(cand); tie path
// only fires at attained values so float ==/> at T are consistent). acc is
// the only big array and can live in AGPRs; selection sets bit-identical.
__global__ __launch_bounds__(256, 2) void k_attn(
    const float* __restrict__ qh, const short* __restrict__ k0,
    const short* __restrict__ k1, const short* __restrict__ k2,
    const short* __restrict__ vt, float* __restrict__ abar)
{
  __shared__ __align__(16) short ks0s[256][36];   // 18432 B
  __shared__ __align__(16) short ks1s[256][36];   // 18432 B
  __shared__ __align__(16) short vts[32][264];    // 16896 B
  __shared__ __align__(16) short pt[4][16][72];   // 9216 B (per-wave P slab)
  __shared__ float sal[256];                       // 1024 B
  __shared__ float keepf[256];                     // 1024 B   total 65024 B

  const int win = blockIdx.x;
  const int bh = win >> 6, l = win & 63;
  const int b = bh >> 2, h = bh & 3;
  const int tid = threadIdx.x;
  const int lane = tid & 63, wv = tid >> 6;
  const int g = lane >> 4, p = lane & 15;
  const int wt = wv;                          // 4 waves, 4 w-tiles

  const float* qw = qh + (size_t)win * 8192;
  const short* kw2 = k2 + (size_t)win * 8192;

  // ---- stage K hi/mid + V^T into LDS ----
  {
    const uint4* s0 = (const uint4*)(k0 + (size_t)win * 8192);
    const uint4* s1 = (const uint4*)(k1 + (size_t)win * 8192);
    const uint4* sv = (const uint4*)(vt + (size_t)win * 8192);
    #pragma unroll
    for (int i = 0; i < 4; ++i) {
      int ci = tid + i * 256;                  // 1024 uint4 per tensor
      int r = ci >> 2, c8 = (ci & 3) * 8;
      *(uint4*)&ks0s[r][c8] = s0[ci];
      *(uint4*)&ks1s[r][c8] = s1[ci];
      int rv = ci >> 5, c16 = (ci & 31) * 8;
      *(uint4*)&vts[rv][c16] = sv[ci];
    }
  }
  // ---- query saliency (FROZEN summation order) ----
  {
    const float4* qg2 = (const float4*)(qw + (size_t)tid * 32);
    float ss = 0.f;
    #pragma unroll
    for (int i = 0; i < 8; ++i) {
      float4 vv = qg2[i];
      ss += vv.x * vv.x + vv.y * vv.y + vv.z * vv.z + vv.w * vv.w;
    }
    sal[tid] = ss;
  }
  __syncthreads();
  if (wv == 0) {                              // exact top-192 saliency (FROZEN)
    float v[4]; bool selq[4];
    #pragma unroll
    for (int s = 0; s < 4; ++s) v[s] = sal[lane + 64 * s];
    topk_sel(v, KEEPQ, lane, selq);
    #pragma unroll
    for (int s = 0; s < 4; ++s) keepf[lane + 64 * s] = selq[s] ? SCALE : 0.0f;
  }
  __syncthreads();

  float4v pacc0 = {0.f, 0.f, 0.f, 0.f};
  float4v pacc1 = {0.f, 0.f, 0.f, 0.f};
  short* ptw = &pt[wv][0][0];                 // [16][72]

  for (int n = 0; n < 4; ++n) {
    const int qbase = n * 64 + wt * 16;
    const float kfp = keepf[qbase + p];       // per-query (col p) keep factor
    const bool kept = (kfp != 0.0f);

    // ---- Q B-fragment: scale+mask then bf16x3 split (FROZEN values) ----
    short8v aq0, aq1, aq2;
    {
      const float* qrow = qw + (size_t)(qbase + p) * 32 + g * 8;
      float4 qa = *(const float4*)qrow;
      float4 qb = *(const float4*)(qrow + 4);
      float qv[8] = {qa.x, qa.y, qa.z, qa.w, qb.x, qb.y, qb.z, qb.w};
      #pragma unroll
      for (int e = 0; e < 8; ++e) {
        short hh, mm, ll;
        split3(qv[e] * kfp, hh, mm, ll);
        aq0[e] = hh; aq1[e] = mm; aq2[e] = ll;
      }
    }

    // ---- QK^T swapped: acc[c][r] = S[key 16c+4g+r][query qbase+p]; FROZEN ----
    float4v acc[16];
    #pragma unroll
    for (int c = 0; c < 16; ++c) {
      const short8v b0 = *(const short8v*)&ks0s[c * 16 + p][g * 8];
      const short8v b1 = *(const short8v*)&ks1s[c * 16 + p][g * 8];
      const short8v b2 = *(const short8v*)(kw2 + (size_t)(c * 16 + p) * 32 + g * 8);
      float4v a = {0.f, 0.f, 0.f, 0.f};
      a = __builtin_amdgcn_mfma_f32_16x16x32_bf16(b0, aq0, a, 0, 0, 0);
      a = __builtin_amdgcn_mfma_f32_16x16x32_bf16(b0, aq1, a, 0, 0, 0);
      a = __builtin_amdgcn_mfma_f32_16x16x32_bf16(b0, aq2, a, 0, 0, 0);
      a = __builtin_amdgcn_mfma_f32_16x16x32_bf16(b1, aq0, a, 0, 0, 0);
      a = __builtin_amdgcn_mfma_f32_16x16x32_bf16(b1, aq1, a, 0, 0, 0);
      a = __builtin_amdgcn_mfma_f32_16x16x32_bf16(b2, aq0, a, 0, 0, 0);
      acc[c] = a;
    }

    // ---- float max/min reduce over the query's 256 keys ----
    float fmx = acc[0][0], fmn = acc[0][0];
    #pragma unroll
    for (int c = 0; c < 16; ++c) {
      #pragma unroll
      for (int r = 0; r < 4; ++r) {
        fmx = fmaxf(fmx, acc[c][r]);
        fmn = fminf(fmn, acc[c][r]);
      }
    }
    fmx = fmaxf(fmx, __shfl_xor(fmx, 16));
    fmn = fminf(fmn, __shfl_xor(fmn, 16));
    fmx = fmaxf(fmx, __shfl_xor(fmx, 32));
    fmn = fminf(fmn, __shfl_xor(fmn, 32));
    const uint32_t umaxu = fmap(fmx), uminu = fmap(fmn);
    const float fm = unmap(umaxu);            // canonical (+0) exact max

    // ---- exact top-64 threshold: bisection with FLOAT compares ----
    uint32_t piv = 0u; int cnt = 256; int sb = -1; bool bdone = true;
    if (kept) {
      uint32_t du = umaxu ^ uminu;
      if (du != 0u) {
        sb = 31 - __clz(du);
        piv = (sb >= 31) ? 0u : (umaxu & (0xFFFFFFFFu << (sb + 1)));
        bdone = false;
      } else { piv = umaxu; }                 // all equal -> tie path
    }
    for (int bit = 31; bit >= 0; --bit) {
      if (__all(bdone)) break;
      const uint32_t cand = piv | (1u << bit);
      const float tf = unmap(cand);
      int cc = 0;
      #pragma unroll
      for (int c = 0; c < 16; ++c) {
        #pragma unroll
        for (int r = 0; r < 4; ++r) cc += (acc[c][r] >= tf) ? 1 : 0;
      }
      cc += __shfl_xor(cc, 16);
      cc += __shfl_xor(cc, 32);
      if (!bdone && bit <= sb && cc >= 64) {
        piv = cand; cnt = cc;
        if (cc == 64) bdone = true;
      }
    }
    const float Tf = unmap(piv);

    // ---- selection mask (bit 4c+r), exact tie-break by key index ----
    uint64_t selm = 0ull;
    if (kept) {
      if (cnt == 64) {
        #pragma unroll
        for (int c = 0; c < 16; ++c)
          #pragma unroll
          for (int r = 0; r < 4; ++r)
            selm |= (acc[c][r] >= Tf) ? (1ull << (4 * c + r)) : 0ull;
      } else {
        // rare: ties at T (T is an attained value -> float ==/> consistent).
        int gtc = 0;
        #pragma unroll
        for (int c = 0; c < 16; ++c)
          #pragma unroll
          for (int r = 0; r < 4; ++r) gtc += (acc[c][r] > Tf) ? 1 : 0;
        gtc += __shfl_xor(gtc, 16);
        gtc += __shfl_xor(gtc, 32);
        const int need = 64 - gtc;
        uint64_t em = 0ull;
        #pragma unroll
        for (int c = 0; c < 16; ++c)
          #pragma unroll
          for (int r = 0; r < 4; ++r)
            em |= (acc[c][r] == Tf) ? (1ull << (4 * c + r)) : 0ull;
        uint64_t emA = __shfl_xor((unsigned long long)em, 16);
        uint64_t emB = __shfl_xor((unsigned long long)em, 32);
        uint64_t emC = __shfl_xor((unsigned long long)emA, 32);
        uint64_t M0 = (g == 0) ? em : ((g == 1) ? emA : ((g == 2) ? emB : emC));
        uint64_t M1 = (g == 1) ? em : ((g == 0) ? emA : ((g == 3) ? emB : emC));
        uint64_t M2 = (g == 2) ? em : ((g == 3) ? emA : ((g == 0) ? emB : emC));
        uint64_t M3 = (g == 3) ? em : ((g == 2) ? emA : ((g == 1) ? emB : emC));
        int pref = 0;
        #pragma unroll
        for (int c = 0; c < 16; ++c) {
          int n0 = (int)((M0 >> (4 * c)) & 15ull);
          int n1 = (int)((M1 >> (4 * c)) & 15ull);
          int n2 = (int)((M2 >> (4 * c)) & 15ull);
          int n3 = (int)((M3 >> (4 * c)) & 15ull);
          int gs = ((g > 0) ? __popc(n0) : 0) + ((g > 1) ? __popc(n1) : 0)
                 + ((g > 2) ? __popc(n2) : 0);
          int on = (int)((em >> (4 * c)) & 15ull);
          #pragma unroll
          for (int r = 0; r < 4; ++r) {
            bool s2;
            if (acc[c][r] > Tf) s2 = true;
            else if (acc[c][r] == Tf) {
              int before = pref + gs + __popc(on & ((1 << r) - 1));
              s2 = (before < need);
            } else s2 = false;
            selm |= s2 ? (1ull << (4 * c + r)) : 0ull;
          }
          pref += __popc(n0) + __popc(n1) + __popc(n2) + __popc(n3);
        }
      }
    }

    // ---- e = exp(S - fm) on selected; OVERWRITE acc in place; esum (FROZEN) ----
    float esum = 0.f;
    #pragma unroll
    for (int c = 0; c < 16; ++c) {
      #pragma unroll
      for (int r = 0; r < 4; ++r) {
        float e;
        if (kept)
          e = ((selm >> (4 * c + r)) & 1ull) ? __expf(acc[c][r] - fm) : 0.0f;
        else
          e = (c < 4) ? 0.015625f : 0.0f;    // pruned: uniform 1/64 over first 64 keys
        acc[c][r] = e;
        esum += e;
      }
    }
    esum += __shfl_xor(esum, 16);
    esum += __shfl_xor(esum, 32);
    const float inv = kept ? (1.0f / esum) : 1.0f;

    // ---- PV: stage P^T per 2-kk block, then MFMA (FROZEN chain order) ----
    #pragma unroll
    for (int t = 0; t < 4; ++t) {
      #pragma unroll
      for (int kq = 0; kq < 2; ++kq) {
        const int kk = 2 * t + kq;
        const int ce = 2 * kk, co = ce + 1;
        uint2 w0 = make_uint2(pk2(f2bf(acc[ce][0] * inv), f2bf(acc[ce][1] * inv)),
                              pk2(f2bf(acc[ce][2] * inv), f2bf(acc[ce][3] * inv)));
        uint2 w1 = make_uint2(pk2(f2bf(acc[co][0] * inv), f2bf(acc[co][1] * inv)),
                              pk2(f2bf(acc[co][2] * inv), f2bf(acc[co][3] * inv)));
        *(uint2*)&ptw[p * 72 + kq * 32 + 4 * g] = w0;
        *(uint2*)&ptw[p * 72 + kq * 32 + 16 + 4 * g] = w1;
      }
      // cross-lane visibility of this wave's writes (no HIP-level dependency)
      asm volatile("s_waitcnt lgkmcnt(0)" ::: "memory");
      __builtin_amdgcn_sched_barrier(0);
      #pragma unroll
      for (int kq = 0; kq < 2; ++kq) {
        const int kk = 2 * t + kq;
        short8v pa = *(const short8v*)&ptw[p * 72 + kq * 32 + 8 * g];
        short8v v0 = *(const short8v*)&vts[p][kk * 32 + 8 * g];
        short8v v1 = *(const short8v*)&vts[16 + p][kk * 32 + 8 * g];
        pacc0 = __builtin_amdgcn_mfma_f32_16x16x32_bf16(pa, v0, pacc0, 0, 0, 0);
        pacc1 = __builtin_amdgcn_mfma_f32_16x16x32_bf16(pa, v1, pacc1, 0, 0, 0);
      }
    }
  }

  // ---- write abar = mean over n (each wave owns its w-tile; no reduction) ----
  #pragma unroll
  for (int rr = 0; rr < 4; ++rr) {
    const int w = wt * 16 + g * 4 + rr;
    size_t o = ((size_t)(b * 64 + l) * 64 + w) * 128 + h * 32;
    abar[o + p] = pacc0[rr] * 0.25f;
    abar[o + 16 + p] = pacc1[rr] * 0.25f;
  }
}

// ---------------- Kernel 3: final projection (FROZEN) ----------------
__global__ __launch_bounds__(256) void k_proj(
    const float* __restrict__ abar, const float* __restrict__ W,
    const float* __restrict__ bi, float* __restrict__ out)
{
  __shared__ float xs[64 * 132];
  const int tile = blockIdx.x;
  const int tid = threadIdx.x;
  const float4* xg = (const float4*)(abar + (size_t)tile * 64 * 128);
  #pragma unroll
  for (int i = 0; i < 8; ++i) {
    int idx = tid + i * 256;
    int r = idx >> 5, c = (idx & 31) * 4;
    *(float4*)&xs[r * 132 + c] = xg[idx];
  }
  __syncthreads();

  const int ty = tid >> 4, tx = tid & 15;
  float acc[4][8];
  #pragma unroll
  for (int i = 0; i < 4; ++i)
    #pragma unroll
    for (int j = 0; j < 8; ++j) acc[i][j] = 0.f;

  #pragma unroll 2
  for (int kk = 0; kk < 128; kk += 4) {
    float aa[4][4];
    #pragma unroll
    for (int i = 0; i < 4; ++i)
      *(float4*)&aa[i][0] = *(const float4*)&xs[(ty * 4 + i) * 132 + kk];
    #pragma unroll
    for (int t2 = 0; t2 < 4; ++t2) {
      const float4 w0 = *(const float4*)&W[(kk + t2) * 128 + tx * 8];
      const float4 w1 = *(const float4*)&W[(kk + t2) * 128 + tx * 8 + 4];
      #pragma unroll
      for (int i = 0; i < 4; ++i) {
        acc[i][0] = fmaf(aa[i][t2], w0.x, acc[i][0]);
        acc[i][1] = fmaf(aa[i][t2], w0.y, acc[i][1]);
        acc[i][2] = fmaf(aa[i][t2], w0.z, acc[i][2]);
        acc[i][3] = fmaf(aa[i][t2], w0.w, acc[i][3]);
        acc[i][4] = fmaf(aa[i][t2], w1.x, acc[i][4]);
        acc[i][5] = fmaf(aa[i][t2], w1.y, acc[i][5]);
        acc[i][6] = fmaf(aa[i][t2], w1.z, acc[i][6]);
        acc[i][7] = fmaf(aa[i][t2], w1.w, acc[i][7]);
      }
    }
  }
  #pragma unroll
  for (int i = 0; i < 4; ++i) {
    size_t row = (size_t)tile * 64 + ty * 4 + i;
    float4 o0 = make_float4(acc[i][0] + bi[tx * 8 + 0], acc[i][1] + bi[tx * 8 + 1],
                            acc[i][2] + bi[tx * 8 + 2], acc[i][3] + bi[tx * 8 + 3]);
    float4 o1 = make_float4(acc[i][4] + bi[tx * 8 + 4], acc[i][5] + bi[tx * 8 + 5],
                            acc[i][6] + bi[tx * 8 + 6], acc[i][7] + bi[tx * 8 + 7]);
    *(float4*)&out[row * 128 + tx * 8] = o0;
    *(float4*)&out[row * 128 + tx * 8 + 4] = o1;
  }
}

extern "C" void kernel_launch(void* const* d_in, const int* in_sizes, int n_in,
                              void* d_out, int out_size, void* d_ws, size_t ws_size,
                              hipStream_t stream) {
  (void)in_sizes; (void)n_in; (void)out_size; (void)ws_size;
  const float* xq   = (const float*)d_in[0];
  const float* xk   = (const float*)d_in[1];
  const float* xv   = (const float*)d_in[2];
  const float* gq   = (const float*)d_in[3];
  const float* beq  = (const float*)d_in[4];
  const float* gk   = (const float*)d_in[5];
  const float* bek  = (const float*)d_in[6];
  const float* gv   = (const float*)d_in[7];
  const float* bev  = (const float*)d_in[8];
  const float* wq   = (const float*)d_in[9];
  const float* biq  = (const float*)d_in[10];
  const float* wk   = (const float*)d_in[11];
  const float* bik  = (const float*)d_in[12];
  const float* wv   = (const float*)d_in[13];
  const float* biv  = (const float*)d_in[14];
  const float* wpr  = (const float*)d_in[15];
  const float* bpr  = (const float*)d_in[16];

  // ws layout (109,051,904 B total == proven footprint):
  char* ws = (char*)d_ws;
  float* qh  = (float*)(ws);                       // 33,554,432 B
  short* k0  = (short*)(ws + 33554432);            // 16,777,216 B
  short* k1  = (short*)(ws + 50331648);            // 16,777,216 B
  short* k2  = (short*)(ws + 67108864);            // 16,777,216 B
  short* vt  = (short*)(ws + 83886080);            // 16,777,216 B
  float* abar = (float*)(ws + 100663296);          //  8,388,608 B

  k_lnproj<<<dim3(1024, 3), 256, 0, stream>>>(xq, xk, xv, gq, beq, gk, bek, gv, bev,
                                              wq, biq, wk, bik, wv, biv,
                                              qh, k0, k1, k2, vt);
  k_attn<<<1024, 256, 0, stream>>>(qh, k0, k1, k2, vt, abar);
  k_proj<<<256, 256, 0, stream>>>(abar, wpr, bpr, (float*)d_out);
}